// Round 13
// baseline (148.389 us; speedup 1.0000x reference)
//
#include <hip/hip_runtime.h>
#include <hip/hip_bf16.h>
#include <math.h>

#define B_    4
#define T_    4096
#define E_    768
#define H_    6
#define D_    64
#define HD_   384
#define G_    1024
#define RATIO_ 4
#define TOPK_ 8
#define MT_   (B_*T_)   // 16384 rows total
#define NS_   1152      // stacked N: [384 q][768 kg-interleaved]

typedef __attribute__((ext_vector_type(8))) short short8;
typedef __attribute__((ext_vector_type(4))) float f32x4;
typedef __hip_bfloat16 bf16;

#define GLD16(g, l) __builtin_amdgcn_global_load_lds( \
    (const __attribute__((address_space(1))) void*)(g), \
    (__attribute__((address_space(3))) void*)(l), 16, 0, 0)

static __device__ __forceinline__ unsigned short f2bf(float f) {
  bf16 h = __float2bfloat16(f);
  return __builtin_bit_cast(unsigned short, h);
}
static __device__ __forceinline__ unsigned umax_(unsigned a, unsigned b) { return a > b ? a : b; }
static __device__ __forceinline__ unsigned umin_(unsigned a, unsigned b) { return a > b ? b : a; }

// ---------------------------------------------------------------------------
// x f32 -> bf16 (8 elems/thread)
// ---------------------------------------------------------------------------
__global__ __launch_bounds__(256) void cvt_x_kernel(
    const float* __restrict__ in, bf16* __restrict__ out)
{
  size_t i = (size_t)blockIdx.x * 256 + threadIdx.x;
  const float4* p = reinterpret_cast<const float4*>(in) + i * 2;
  float4 v0 = p[0], v1 = p[1];
  float f[8] = {v0.x, v0.y, v0.z, v0.w, v1.x, v1.y, v1.z, v1.w};
  union { unsigned short u[8]; short8 v; } r;
#pragma unroll
  for (int k = 0; k < 8; ++k) r.u[k] = f2bf(f[k]);
  *reinterpret_cast<short8*>(out + i * 8) = r.v;
}

// ---------------------------------------------------------------------------
// transpose+convert+STACK weights into Ws [1152][768] bf16:
//   q col c -> row c ; k col c -> row 384+(c>>4)*32+(c&15) ; g -> +16
// ---------------------------------------------------------------------------
__global__ __launch_bounds__(256) void cvt_w_t(
    const float* __restrict__ wq, const float* __restrict__ wk,
    const float* __restrict__ wg, bf16* __restrict__ outbase)
{
  const int z = blockIdx.z;
  const float* src = z == 0 ? wq : (z == 1 ? wk : wg);
  __shared__ float t[32][33];
  int r = threadIdx.x >> 5, c = threadIdx.x & 31;
  int k0 = blockIdx.x * 32, n0 = blockIdx.y * 32;
#pragma unroll
  for (int i = 0; i < 4; ++i)
    t[r + i * 8][c] = src[(size_t)(k0 + r + i * 8) * HD_ + n0 + c];
  __syncthreads();
#pragma unroll
  for (int i = 0; i < 4; ++i) {
    int cc = n0 + r + i * 8;
    int ro = (z == 0) ? cc : 384 + ((cc >> 4) << 5) + ((z - 1) << 4) + (cc & 15);
    outbase[(size_t)ro * E_ + k0 + c] = __float2bfloat16(t[c][r + i * 8]);
  }
}

// ---------------------------------------------------------------------------
// Fused projection GEMM, 2Mx2N waves (wave-tile 64x64): halves the LDS-read
// amplification vs M-stacked (B read by 2 waves not 4; A direct from global).
// A: 4 short8/wave/K-step, prefetched 1 iter. B: 3-ring LDS + counted vmcnt
// (queue {S(k)2,A(k)4,S(k+1)2,A(k+1)4,S(k+2)2}=14, retire 6 -> vmcnt(8)).
// ---------------------------------------------------------------------------
__global__ __launch_bounds__(256, 2) void gemm_qkg_mfma(
    const bf16* __restrict__ X, const bf16* __restrict__ Ws,
    const float* __restrict__ ape, bf16* __restrict__ Q,
    bf16* __restrict__ keys)
{
  __shared__ bf16 lds[3][4096];   // B tile [128 rows][32 k] per buf = 8KB
  __shared__ float ssx[2][2][4][4];  // kg cross-wave rmsnorm partials
  const int tid = threadIdx.x;
  const int lane = tid & 63, wv = tid >> 6;
  const int wm = wv >> 1, wn = wv & 1;
  const int ll = lane & 15, lh = lane >> 4;
  const int m0 = blockIdx.x * 128, n0 = blockIdx.y * 128;
  const int srow = tid >> 2;
  const int scol = (((tid & 3) ^ ((tid >> 3) & 3)) << 3);  // swizzled src slot
  const bf16* pB0 = Ws + (size_t)(n0 + srow) * E_ + scol;
  const bf16* pB1 = Ws + (size_t)(n0 + 64 + srow) * E_ + scol;
  const bf16* pA[4];
#pragma unroll
  for (int r = 0; r < 4; ++r)
    pA[r] = X + (size_t)(m0 + wm * 64 + r * 16 + ll) * E_ + lh * 8;

#define STAGE(b, k0) do { \
    char* base_ = (char*)&lds[b][0] + tid * 16; \
    GLD16(pB0 + (k0), base_); \
    GLD16(pB1 + (k0), base_ + 4096); \
  } while (0)

  f32x4 acc[4][4];
#pragma unroll
  for (int m = 0; m < 4; ++m)
#pragma unroll
    for (int n = 0; n < 4; ++n) acc[m][n] = (f32x4){0.f, 0.f, 0.f, 0.f};
  const int asw = (lh ^ ((ll >> 1) & 3)) << 3;  // swizzled read slot (elems)

  short8 curA[4], nxtA[4];
#pragma unroll
  for (int r = 0; r < 4; ++r) curA[r] = *reinterpret_cast<const short8*>(pA[r]);
  STAGE(0, 0);
  STAGE(1, 32);
#pragma unroll
  for (int r = 0; r < 4; ++r) nxtA[r] = curA[r];

#pragma unroll
  for (int k = 0; k < 24; ++k) {
    const int k0 = k * 32;
    if (k < 23) {
#pragma unroll
      for (int r = 0; r < 4; ++r)
        nxtA[r] = *reinterpret_cast<const short8*>(pA[r] + k0 + 32);
    }
    if (k < 22) STAGE((k + 2) % 3, k0 + 64);
    if (k < 22)       asm volatile("s_waitcnt vmcnt(8)" ::: "memory");
    else if (k == 22) asm volatile("s_waitcnt vmcnt(6)" ::: "memory");
    else              asm volatile("s_waitcnt vmcnt(0)" ::: "memory");
    __builtin_amdgcn_s_barrier();
    __builtin_amdgcn_sched_barrier(0);
    const bf16* Lb = &lds[k % 3][0];
    short8 b[4];
#pragma unroll
    for (int n = 0; n < 4; ++n)
      b[n] = *reinterpret_cast<const short8*>(
          &Lb[(wn * 64 + n * 16 + ll) * 32 + asw]);
    asm volatile("s_waitcnt lgkmcnt(0)" ::: "memory");
    __builtin_amdgcn_sched_barrier(0);
    __builtin_amdgcn_s_barrier();
#pragma unroll
    for (int m = 0; m < 4; ++m)
#pragma unroll
      for (int n = 0; n < 4; ++n)
        acc[m][n] = __builtin_amdgcn_mfma_f32_16x16x32_bf16(curA[m], b[n], acc[m][n], 0, 0, 0);
#pragma unroll
    for (int r = 0; r < 4; ++r) curA[r] = nxtA[r];
  }
#undef STAGE

  if (blockIdx.y < 3) {
    // q epilogue: wave = one full 64-col head; rmsnorm per row
#pragma unroll
    for (int m = 0; m < 4; ++m)
#pragma unroll
      for (int j = 0; j < 4; ++j) {
        float ss = 0.f;
#pragma unroll
        for (int n = 0; n < 4; ++n) ss += acc[m][n][j] * acc[m][n][j];
        ss += __shfl_xor(ss, 1, 64); ss += __shfl_xor(ss, 2, 64);
        ss += __shfl_xor(ss, 4, 64); ss += __shfl_xor(ss, 8, 64);
        float scl = rsqrtf(ss * (1.0f / D_) + 1e-6f);
        int row = m0 + wm * 64 + m * 16 + lh * 4 + j;
#pragma unroll
        for (int n = 0; n < 4; ++n)
          Q[(size_t)row * HD_ + n0 + wn * 64 + n * 16 + ll] =
              __float2bfloat16(acc[m][n][j] * scl);
      }
  } else {
    // kg epilogue: wave holds 2 k/g slot-pairs = 32 head-cols of the head;
    // softmax-pool lane-locally, rmsnorm needs the other wn-wave's partial.
    const int hcb = (n0 - 384) >> 1;
    float apev[2][4];
#pragma unroll
    for (int p = 0; p < 2; ++p) {
      int hc = hcb + (wn * 2 + p) * 16 + ll;
#pragma unroll
      for (int j = 0; j < 4; ++j) apev[p][j] = ape[j * HD_ + hc];
    }
    float pooled[4][2];
#pragma unroll
    for (int m = 0; m < 4; ++m) {
#pragma unroll
      for (int p = 0; p < 2; ++p) {
        float g0 = acc[m][2 * p + 1][0] + apev[p][0];
        float g1 = acc[m][2 * p + 1][1] + apev[p][1];
        float g2 = acc[m][2 * p + 1][2] + apev[p][2];
        float g3 = acc[m][2 * p + 1][3] + apev[p][3];
        float mx = fmaxf(fmaxf(g0, g1), fmaxf(g2, g3));
        float e0 = expf(g0 - mx), e1 = expf(g1 - mx);
        float e2 = expf(g2 - mx), e3 = expf(g3 - mx);
        float inv = 1.0f / (e0 + e1 + e2 + e3);
        pooled[m][p] = (acc[m][2 * p][0] * e0 + acc[m][2 * p][1] * e1 +
                        acc[m][2 * p][2] * e2 + acc[m][2 * p][3] * e3) * inv;
      }
      float ss = pooled[m][0] * pooled[m][0] + pooled[m][1] * pooled[m][1];
      ss += __shfl_xor(ss, 1, 64); ss += __shfl_xor(ss, 2, 64);
      ss += __shfl_xor(ss, 4, 64); ss += __shfl_xor(ss, 8, 64);
      if (ll == 0) ssx[wm][wn][m][lh] = ss;
    }
    __syncthreads();
#pragma unroll
    for (int m = 0; m < 4; ++m) {
      float ss = ssx[wm][0][m][lh] + ssx[wm][1][m][lh];
      float scl = rsqrtf(ss * (1.0f / D_) + 1e-6f);
      int prow = (m0 >> 2) + wm * 16 + m * 4 + lh;
#pragma unroll
      for (int p = 0; p < 2; ++p)
        keys[(size_t)prow * HD_ + hcb + (wn * 2 + p) * 16 + ll] =
            __float2bfloat16(pooled[m][p] * scl);
    }
  }
}

// ---------------------------------------------------------------------------
// FUSED score + top-8 + mask write (R11 structure: 4 waves/block, qf in regs)
// + sorting networks replacing the serial insert (dep depth 256 -> ~14).
// ---------------------------------------------------------------------------
__global__ __launch_bounds__(256, 4) void score_topk_fused(
    const bf16* __restrict__ Qall, const bf16* __restrict__ Kall,
    int* __restrict__ mask, int* __restrict__ ends)
{
  const int x = blockIdx.x;                 // 0..255
  const int b = blockIdx.y;                 // batch
  const int s = (b < 2) ? x : 255 - x;      // complementary balance pairing
  const int t0 = s << 4;
  const int tid = threadIdx.x;
  const int w = tid >> 6;                   // wave 0..3
  const int lane = tid & 63;
  const int ll = lane & 15, lh = lane >> 4;

  __shared__ unsigned top[4][16][8];        // per-wave top-8 per row

  if (x == 0 && b == 0) {                   // group_ends (once)
    int g = tid;
#pragma unroll
    for (int c = 0; c < 4; ++c, g += 256) {
      int e = (g << 2) + 3;
      ends[g] = e < T_ - 1 ? e : T_ - 1;
    }
  }

  // zero-fill the strip's 16 mask rows (overlaps compute; drained by sync)
  int* mbase = mask + ((size_t)b * T_ + t0) * G_;
  {
    int4* m4 = reinterpret_cast<int4*>(mbase);
    const int4 z = make_int4(0, 0, 0, 0);
#pragma unroll
    for (int i = 0; i < 16; ++i) m4[i * 256 + tid] = z;
  }

  const bf16* Qb = Qall + (size_t)b * T_ * HD_;
  const bf16* Kb = Kall + (size_t)b * G_ * HD_;
  const int t = t0 + ll;                    // this lane's row
  const int gmax = (t + 1) >> 2;
  const int nmega = ((t0 >> 2) + 4 + 63) >> 6;   // 64-g mega-tiles in strip

  // q panel: 12 k-frags (B-operand: col=ll -> t, k-slice lh*8)
  short8 qf[12];
  {
    const bf16* pQ = Qb + (size_t)t * HD_ + lh * 8;
#pragma unroll
    for (int k = 0; k < 12; ++k)
      qf[k] = *reinterpret_cast<const short8*>(pQ + k * 32);
  }

  unsigned v0 = 0, v1 = 0, v2 = 0, v3 = 0, v4 = 0, v5 = 0, v6 = 0, v7 = 0;

#define CEx(a, bb) { unsigned h_ = umax_(a, bb), l_ = umin_(a, bb); a = h_; bb = l_; }
#define SORT8(A, o) do { \
    CEx(A[o+0],A[o+1]); CEx(A[o+2],A[o+3]); CEx(A[o+4],A[o+5]); CEx(A[o+6],A[o+7]); \
    CEx(A[o+0],A[o+2]); CEx(A[o+1],A[o+3]); CEx(A[o+4],A[o+6]); CEx(A[o+5],A[o+7]); \
    CEx(A[o+1],A[o+2]); CEx(A[o+5],A[o+6]); \
    CEx(A[o+0],A[o+4]); CEx(A[o+1],A[o+5]); CEx(A[o+2],A[o+6]); CEx(A[o+3],A[o+7]); \
    CEx(A[o+2],A[o+4]); CEx(A[o+3],A[o+5]); \
    CEx(A[o+1],A[o+2]); CEx(A[o+3],A[o+4]); CEx(A[o+5],A[o+6]); \
  } while (0)
#define CLEAN8(E) do { \
    CEx(E[0],E[4]); CEx(E[1],E[5]); CEx(E[2],E[6]); CEx(E[3],E[7]); \
    CEx(E[0],E[2]); CEx(E[1],E[3]); CEx(E[4],E[6]); CEx(E[5],E[7]); \
    CEx(E[0],E[1]); CEx(E[2],E[3]); CEx(E[4],E[5]); CEx(E[6],E[7]); \
  } while (0)

  for (int mg = w; mg < nmega; mg += 4) {   // waves split mega-tiles
    const int g0 = mg << 6;
    const bf16* pK = Kb + (size_t)(g0 + ll) * HD_ + lh * 8;
    short8 kf[12][4];
#pragma unroll
    for (int kk = 0; kk < 12; ++kk)
#pragma unroll
      for (int tl = 0; tl < 4; ++tl)
        kf[kk][tl] = *reinterpret_cast<const short8*>(
            pK + (size_t)tl * 16 * HD_ + kk * 32);
    f32x4 acc[4];
#pragma unroll
    for (int tl = 0; tl < 4; ++tl) acc[tl] = (f32x4){0.f, 0.f, 0.f, 0.f};
#pragma unroll
    for (int kk = 0; kk < 12; ++kk)
#pragma unroll
      for (int tl = 0; tl < 4; ++tl)
        acc[tl] = __builtin_amdgcn_mfma_f32_16x16x32_bf16(
            kf[kk][tl], qf[kk], acc[tl], 0, 0, 0);
    // |dot| < 384 (Cauchy-Schwarz, rmsnorm'd operands) -> dot+512 > 0:
    // positive f32 bits are order-isomorphic to u32.
    unsigned c[16];
#pragma unroll
    for (int tl = 0; tl < 4; ++tl)
#pragma unroll
      for (int j = 0; j < 4; ++j) {
        int g = g0 + tl * 16 + lh * 4 + j;
        float xv = acc[tl][j] + 512.0f;
        c[tl * 4 + j] = (g < gmax)
            ? ((__builtin_bit_cast(unsigned, xv) & 0xFFFFFC00u) |
               (unsigned)(1023 - g))
            : 0u;
      }
    SORT8(c, 0);
    SORT8(c, 8);
    unsigned e[8];
#pragma unroll
    for (int i = 0; i < 8; ++i) e[i] = umax_(c[i], c[15 - i]);
    CLEAN8(e);
    unsigned nv[8];
    nv[0] = umax_(v0, e[7]); nv[1] = umax_(v1, e[6]);
    nv[2] = umax_(v2, e[5]); nv[3] = umax_(v3, e[4]);
    nv[4] = umax_(v4, e[3]); nv[5] = umax_(v5, e[2]);
    nv[6] = umax_(v6, e[1]); nv[7] = umax_(v7, e[0]);
    CLEAN8(nv);
    v0 = nv[0]; v1 = nv[1]; v2 = nv[2]; v3 = nv[3];
    v4 = nv[4]; v5 = nv[5]; v6 = nv[6]; v7 = nv[7];
  }

#define MERGE4() \
  _Pragma("unroll") \
  for (int st = 0; st < 2; ++st) { \
    const int off = 16 << st; \
    unsigned p0 = (unsigned)__shfl_xor((int)v0, off, 64); \
    unsigned p1 = (unsigned)__shfl_xor((int)v1, off, 64); \
    unsigned p2 = (unsigned)__shfl_xor((int)v2, off, 64); \
    unsigned p3 = (unsigned)__shfl_xor((int)v3, off, 64); \
    unsigned p4 = (unsigned)__shfl_xor((int)v4, off, 64); \
    unsigned p5 = (unsigned)__shfl_xor((int)v5, off, 64); \
    unsigned p6 = (unsigned)__shfl_xor((int)v6, off, 64); \
    unsigned p7 = (unsigned)__shfl_xor((int)v7, off, 64); \
    unsigned w0 = umax_(v0, p7), w1 = umax_(v1, p6); \
    unsigned w2 = umax_(v2, p5), w3 = umax_(v3, p4); \
    unsigned w4 = umax_(v4, p3), w5 = umax_(v5, p2); \
    unsigned w6 = umax_(v6, p1), w7 = umax_(v7, p0); \
    CEx(w0, w4); CEx(w1, w5); CEx(w2, w6); CEx(w3, w7); \
    CEx(w0, w2); CEx(w1, w3); CEx(w4, w6); CEx(w5, w7); \
    CEx(w0, w1); CEx(w2, w3); CEx(w4, w5); CEx(w6, w7); \
    v0 = w0; v1 = w1; v2 = w2; v3 = w3; v4 = w4; v5 = w5; v6 = w6; v7 = w7; \
  }

  MERGE4();                                  // intra-wave: merge 4 lh-lanes

  if (lh == 0) {                             // wave-local result -> LDS
    unsigned* tp = &top[w][ll][0];
    tp[0] = v0; tp[1] = v1; tp[2] = v2; tp[3] = v3;
    tp[4] = v4; tp[5] = v5; tp[6] = v6; tp[7] = v7;
  }
  __syncthreads();                           // also drains zero-fill stores

  if (w == 0) {                              // inter-wave merge + scatter
    const unsigned* tp = &top[lh][ll][0];
    v0 = tp[0]; v1 = tp[1]; v2 = tp[2]; v3 = tp[3];
    v4 = tp[4]; v5 = tp[5]; v6 = tp[6]; v7 = tp[7];
    MERGE4();
    if (lh == 0) {
      int* rb = mbase + (size_t)ll * G_;
      if (v0) rb[1023 - (v0 & 1023)] = 1;
      if (v1) rb[1023 - (v1 & 1023)] = 1;
      if (v2) rb[1023 - (v2 & 1023)] = 1;
      if (v3) rb[1023 - (v3 & 1023)] = 1;
      if (v4) rb[1023 - (v4 & 1023)] = 1;
      if (v5) rb[1023 - (v5 & 1023)] = 1;
      if (v6) rb[1023 - (v6 & 1023)] = 1;
      if (v7) rb[1023 - (v7 & 1023)] = 1;
    }
  }
#undef MERGE4
#undef CLEAN8
#undef SORT8
#undef CEx
}

extern "C" void kernel_launch(void* const* d_in, const int* in_sizes, int n_in,
                              void* d_out, int out_size, void* d_ws, size_t ws_size,
                              hipStream_t stream)
{
  const float* x   = (const float*)d_in[0];
  const float* wq  = (const float*)d_in[1];
  const float* wk  = (const float*)d_in[2];
  const float* wg  = (const float*)d_in[3];
  const float* ape = (const float*)d_in[4];

  // ws layout (bf16): Ws[1152][768] | q[16384][384] | keys[4096][384]
  bf16* Ws   = (bf16*)d_ws;
  bf16* qb   = Ws + (size_t)NS_ * E_;
  bf16* keys = qb + (size_t)MT_ * HD_;

  // x_bf16 staged in d_out (dead before the mask write overwrites it)
  bf16* xb = (bf16*)d_out;

  cvt_x_kernel<<<dim3(MT_ * E_ / 8 / 256), dim3(256), 0, stream>>>(x, xb);
  cvt_w_t<<<dim3(E_ / 32, HD_ / 32, 3), dim3(256), 0, stream>>>(wq, wk, wg, Ws);

  gemm_qkg_mfma<<<dim3(MT_ / 128, NS_ / 128), dim3(256), 0, stream>>>(
      xb, Ws, ape, qb, keys);

  score_topk_fused<<<dim3(256, B_), dim3(256), 0, stream>>>(
      qb, keys, (int*)d_out, (int*)d_out + (size_t)B_ * T_ * G_);
}

// Round 14
// 143.612 us; speedup vs baseline: 1.0333x; 1.0333x over previous
//
#include <hip/hip_runtime.h>
#include <hip/hip_bf16.h>
#include <math.h>

#define B_    4
#define T_    4096
#define E_    768
#define H_    6
#define D_    64
#define HD_   384
#define G_    1024
#define RATIO_ 4
#define TOPK_ 8
#define MT_   (B_*T_)   // 16384 rows total
#define NS_   1152      // stacked N: [384 q][768 kg-interleaved]

typedef __attribute__((ext_vector_type(8))) short short8;
typedef __attribute__((ext_vector_type(4))) float f32x4;
typedef __hip_bfloat16 bf16;

#define GLD16(g, l) __builtin_amdgcn_global_load_lds( \
    (const __attribute__((address_space(1))) void*)(g), \
    (__attribute__((address_space(3))) void*)(l), 16, 0, 0)

static __device__ __forceinline__ unsigned short f2bf(float f) {
  bf16 h = __float2bfloat16(f);
  return __builtin_bit_cast(unsigned short, h);
}
static __device__ __forceinline__ unsigned umax_(unsigned a, unsigned b) { return a > b ? a : b; }
static __device__ __forceinline__ unsigned umin_(unsigned a, unsigned b) { return a > b ? b : a; }

// ---------------------------------------------------------------------------
// x f32 -> bf16 (8 elems/thread)
// ---------------------------------------------------------------------------
__global__ __launch_bounds__(256) void cvt_x_kernel(
    const float* __restrict__ in, bf16* __restrict__ out)
{
  size_t i = (size_t)blockIdx.x * 256 + threadIdx.x;
  const float4* p = reinterpret_cast<const float4*>(in) + i * 2;
  float4 v0 = p[0], v1 = p[1];
  float f[8] = {v0.x, v0.y, v0.z, v0.w, v1.x, v1.y, v1.z, v1.w};
  union { unsigned short u[8]; short8 v; } r;
#pragma unroll
  for (int k = 0; k < 8; ++k) r.u[k] = f2bf(f[k]);
  *reinterpret_cast<short8*>(out + i * 8) = r.v;
}

// ---------------------------------------------------------------------------
// transpose+convert+STACK weights into Ws [1152][768] bf16:
//   q col c -> row c ; k col c -> row 384+(c>>4)*32+(c&15) ; g -> +16
// ---------------------------------------------------------------------------
__global__ __launch_bounds__(256) void cvt_w_t(
    const float* __restrict__ wq, const float* __restrict__ wk,
    const float* __restrict__ wg, bf16* __restrict__ outbase)
{
  const int z = blockIdx.z;
  const float* src = z == 0 ? wq : (z == 1 ? wk : wg);
  __shared__ float t[32][33];
  int r = threadIdx.x >> 5, c = threadIdx.x & 31;
  int k0 = blockIdx.x * 32, n0 = blockIdx.y * 32;
#pragma unroll
  for (int i = 0; i < 4; ++i)
    t[r + i * 8][c] = src[(size_t)(k0 + r + i * 8) * HD_ + n0 + c];
  __syncthreads();
#pragma unroll
  for (int i = 0; i < 4; ++i) {
    int cc = n0 + r + i * 8;
    int ro = (z == 0) ? cc : 384 + ((cc >> 4) << 5) + ((z - 1) << 4) + (cc & 15);
    outbase[(size_t)ro * E_ + k0 + c] = __float2bfloat16(t[c][r + i * 8]);
  }
}

// ---------------------------------------------------------------------------
// ONE fused projection GEMM (R9 structure, best measured 49.6us):
// [MT x 768] @ Ws^T -> q (rmsnormed) + keys (pooled+rmsnormed).
// 128x128 tile, 4 waves stacked in M (wave 32x128, acc 2x8).
// A: direct global->reg prefetched 1 iter. B: 3-ring LDS + counted vmcnt.
// ---------------------------------------------------------------------------
__global__ __launch_bounds__(256, 3) void gemm_qkg_mfma(
    const bf16* __restrict__ X, const bf16* __restrict__ Ws,
    const float* __restrict__ ape, bf16* __restrict__ Q,
    bf16* __restrict__ keys)
{
  __shared__ bf16 lds[3][4096];   // [128 rows][32 k] per buf = 8KB
  const int tid = threadIdx.x;
  const int lane = tid & 63, wv = tid >> 6;
  const int ll = lane & 15, lh = lane >> 4;
  const int m0 = blockIdx.x * 128, n0 = blockIdx.y * 128;
  const int srow = tid >> 2;
  const int scol = (((tid & 3) ^ ((tid >> 3) & 3)) << 3);  // swizzled src slot
  const bf16* pB0 = Ws + (size_t)(n0 + srow) * E_ + scol;
  const bf16* pB1 = Ws + (size_t)(n0 + 64 + srow) * E_ + scol;
  const bf16* pA0 = X + (size_t)(m0 + wv * 32 + ll) * E_ + lh * 8;
  const bf16* pA1 = pA0 + (size_t)16 * E_;

#define STAGE(b, k0) do { \
    char* base_ = (char*)&lds[b][0] + tid * 16; \
    GLD16(pB0 + (k0), base_); \
    GLD16(pB1 + (k0), base_ + 4096); \
  } while (0)

  f32x4 acc[2][8];
#pragma unroll
  for (int m = 0; m < 2; ++m)
#pragma unroll
    for (int n = 0; n < 8; ++n) acc[m][n] = (f32x4){0.f, 0.f, 0.f, 0.f};
  const int asw = (lh ^ ((ll >> 1) & 3)) << 3;  // swizzled read slot (elems)

  short8 curA0 = *reinterpret_cast<const short8*>(pA0);
  short8 curA1 = *reinterpret_cast<const short8*>(pA1);
  STAGE(0, 0);
  STAGE(1, 32);
  short8 nxtA0 = curA0, nxtA1 = curA1;

#pragma unroll
  for (int k = 0; k < 24; ++k) {
    const int k0 = k * 32;
    if (k < 23) {
      nxtA0 = *reinterpret_cast<const short8*>(pA0 + k0 + 32);
      nxtA1 = *reinterpret_cast<const short8*>(pA1 + k0 + 32);
    }
    if (k < 22) STAGE((k + 2) % 3, k0 + 64);
    if (k < 22)       asm volatile("s_waitcnt vmcnt(6)" ::: "memory");
    else if (k == 22) asm volatile("s_waitcnt vmcnt(4)" ::: "memory");
    else              asm volatile("s_waitcnt vmcnt(0)" ::: "memory");
    __builtin_amdgcn_s_barrier();
    __builtin_amdgcn_sched_barrier(0);
    const bf16* Lb = &lds[k % 3][0];
    short8 b[8];
#pragma unroll
    for (int n = 0; n < 8; ++n)
      b[n] = *reinterpret_cast<const short8*>(&Lb[(n * 16 + ll) * 32 + asw]);
    asm volatile("s_waitcnt lgkmcnt(0)" ::: "memory");
    __builtin_amdgcn_sched_barrier(0);
    __builtin_amdgcn_s_barrier();
#pragma unroll
    for (int m = 0; m < 2; ++m) {
      short8 am = (m == 0) ? curA0 : curA1;
#pragma unroll
      for (int n = 0; n < 8; ++n)
        acc[m][n] = __builtin_amdgcn_mfma_f32_16x16x32_bf16(am, b[n], acc[m][n], 0, 0, 0);
    }
    curA0 = nxtA0; curA1 = nxtA1;
  }
#undef STAGE

  if (blockIdx.y < 3) {
    // q epilogue: 2 heads per wave; rmsnorm each 64-col head
#pragma unroll
    for (int m = 0; m < 2; ++m)
#pragma unroll
      for (int j = 0; j < 4; ++j) {
        int row = m0 + wv * 32 + m * 16 + lh * 4 + j;
#pragma unroll
        for (int h = 0; h < 2; ++h) {
          float ss = 0.f;
#pragma unroll
          for (int n = 4 * h; n < 4 * h + 4; ++n) ss += acc[m][n][j] * acc[m][n][j];
          ss += __shfl_xor(ss, 1, 64); ss += __shfl_xor(ss, 2, 64);
          ss += __shfl_xor(ss, 4, 64); ss += __shfl_xor(ss, 8, 64);
          float scl = rsqrtf(ss * (1.0f / D_) + 1e-6f);
#pragma unroll
          for (int n = 4 * h; n < 4 * h + 4; ++n)
            Q[(size_t)row * HD_ + n0 + n * 16 + ll] =
                __float2bfloat16(acc[m][n][j] * scl);
        }
      }
  } else {
    // kg epilogue: frags alternate k,g; pool 4 pairs = full head
    const int hcb = (n0 - 384) >> 1;
    float apev[4][4];
#pragma unroll
    for (int p = 0; p < 4; ++p) {
      int hc = hcb + p * 16 + ll;
#pragma unroll
      for (int j = 0; j < 4; ++j) apev[p][j] = ape[j * HD_ + hc];
    }
#pragma unroll
    for (int m = 0; m < 2; ++m) {
      float pooled[4];
#pragma unroll
      for (int p = 0; p < 4; ++p) {
        float g0 = acc[m][2 * p + 1][0] + apev[p][0];
        float g1 = acc[m][2 * p + 1][1] + apev[p][1];
        float g2 = acc[m][2 * p + 1][2] + apev[p][2];
        float g3 = acc[m][2 * p + 1][3] + apev[p][3];
        float mx = fmaxf(fmaxf(g0, g1), fmaxf(g2, g3));
        float e0 = expf(g0 - mx), e1 = expf(g1 - mx);
        float e2 = expf(g2 - mx), e3 = expf(g3 - mx);
        float inv = 1.0f / (e0 + e1 + e2 + e3);
        pooled[p] = (acc[m][2 * p][0] * e0 + acc[m][2 * p][1] * e1 +
                     acc[m][2 * p][2] * e2 + acc[m][2 * p][3] * e3) * inv;
      }
      float ss = pooled[0] * pooled[0] + pooled[1] * pooled[1] +
                 pooled[2] * pooled[2] + pooled[3] * pooled[3];
      ss += __shfl_xor(ss, 1, 64); ss += __shfl_xor(ss, 2, 64);
      ss += __shfl_xor(ss, 4, 64); ss += __shfl_xor(ss, 8, 64);
      float scl = rsqrtf(ss * (1.0f / D_) + 1e-6f);
      int prow = (m0 >> 2) + wv * 8 + m * 4 + lh;
#pragma unroll
      for (int p = 0; p < 4; ++p)
        keys[(size_t)prow * HD_ + hcb + p * 16 + ll] =
            __float2bfloat16(pooled[p] * scl);
    }
  }
}

// ---------------------------------------------------------------------------
// FUSED score + top-8 + mask write. Block = 8 waves (512 thr) = one 16-row
// strip; launch_bounds(512,4) = 128-VGPR ceiling (qf in regs, NO spills —
// R12's (512,8)=64-VGPR caused scratch spills). Waves split mega-tiles mod 8.
// Sort networks (depth ~14), intra-wave MERGE4, two-phase LDS merge.
// ---------------------------------------------------------------------------
__global__ __launch_bounds__(512, 4) void score_topk_fused(
    const bf16* __restrict__ Qall, const bf16* __restrict__ Kall,
    int* __restrict__ mask, int* __restrict__ ends)
{
  const int x = blockIdx.x;                 // 0..255
  const int b = blockIdx.y;                 // batch
  const int s = (b < 2) ? x : 255 - x;      // complementary balance pairing
  const int t0 = s << 4;
  const int tid = threadIdx.x;
  const int w = tid >> 6;                   // wave 0..7
  const int lane = tid & 63;
  const int ll = lane & 15, lh = lane >> 4;

  __shared__ unsigned top[8][16][8];        // per-wave top-8 per row

  if (x == 0 && b == 0) {                   // group_ends (once)
    int g = tid;
#pragma unroll
    for (int c = 0; c < 2; ++c, g += 512) {
      int e = (g << 2) + 3;
      ends[g] = e < T_ - 1 ? e : T_ - 1;
    }
  }

  // zero-fill the strip's 16 mask rows (overlaps compute; drained by sync)
  int* mbase = mask + ((size_t)b * T_ + t0) * G_;
  {
    int4* m4 = reinterpret_cast<int4*>(mbase);
    const int4 z = make_int4(0, 0, 0, 0);
#pragma unroll
    for (int i = 0; i < 8; ++i) m4[i * 512 + tid] = z;
  }

  const bf16* Qb = Qall + (size_t)b * T_ * HD_;
  const bf16* Kb = Kall + (size_t)b * G_ * HD_;
  const int t = t0 + ll;                    // this lane's row
  const int gmax = (t + 1) >> 2;
  const int nmega = ((t0 >> 2) + 4 + 63) >> 6;   // 64-g mega-tiles in strip

  // q panel: 12 k-frags in registers (B-operand: col=ll -> t, k-slice lh*8)
  short8 qf[12];
  {
    const bf16* pQ = Qb + (size_t)t * HD_ + lh * 8;
#pragma unroll
    for (int k = 0; k < 12; ++k)
      qf[k] = *reinterpret_cast<const short8*>(pQ + k * 32);
  }

  unsigned v0 = 0, v1 = 0, v2 = 0, v3 = 0, v4 = 0, v5 = 0, v6 = 0, v7 = 0;

#define CEx(a, bb) { unsigned h_ = umax_(a, bb), l_ = umin_(a, bb); a = h_; bb = l_; }
#define SORT8(A, o) do { \
    CEx(A[o+0],A[o+1]); CEx(A[o+2],A[o+3]); CEx(A[o+4],A[o+5]); CEx(A[o+6],A[o+7]); \
    CEx(A[o+0],A[o+2]); CEx(A[o+1],A[o+3]); CEx(A[o+4],A[o+6]); CEx(A[o+5],A[o+7]); \
    CEx(A[o+1],A[o+2]); CEx(A[o+5],A[o+6]); \
    CEx(A[o+0],A[o+4]); CEx(A[o+1],A[o+5]); CEx(A[o+2],A[o+6]); CEx(A[o+3],A[o+7]); \
    CEx(A[o+2],A[o+4]); CEx(A[o+3],A[o+5]); \
    CEx(A[o+1],A[o+2]); CEx(A[o+3],A[o+4]); CEx(A[o+5],A[o+6]); \
  } while (0)
#define CLEAN8(E) do { \
    CEx(E[0],E[4]); CEx(E[1],E[5]); CEx(E[2],E[6]); CEx(E[3],E[7]); \
    CEx(E[0],E[2]); CEx(E[1],E[3]); CEx(E[4],E[6]); CEx(E[5],E[7]); \
    CEx(E[0],E[1]); CEx(E[2],E[3]); CEx(E[4],E[5]); CEx(E[6],E[7]); \
  } while (0)

  for (int mg = w; mg < nmega; mg += 8) {   // waves split mega-tiles
    const int g0 = mg << 6;
    const bf16* pK = Kb + (size_t)(g0 + ll) * HD_ + lh * 8;
    short8 kf[12][4];
#pragma unroll
    for (int kk = 0; kk < 12; ++kk)
#pragma unroll
      for (int tl = 0; tl < 4; ++tl)
        kf[kk][tl] = *reinterpret_cast<const short8*>(
            pK + (size_t)tl * 16 * HD_ + kk * 32);
    f32x4 acc[4];
#pragma unroll
    for (int tl = 0; tl < 4; ++tl) acc[tl] = (f32x4){0.f, 0.f, 0.f, 0.f};
#pragma unroll
    for (int kk = 0; kk < 12; ++kk)
#pragma unroll
      for (int tl = 0; tl < 4; ++tl)
        acc[tl] = __builtin_amdgcn_mfma_f32_16x16x32_bf16(
            kf[kk][tl], qf[kk], acc[tl], 0, 0, 0);
    // |dot| < 384 (Cauchy-Schwarz, rmsnorm'd operands) -> dot+512 > 0:
    // positive f32 bits are order-isomorphic to u32.
    unsigned c[16];
#pragma unroll
    for (int tl = 0; tl < 4; ++tl)
#pragma unroll
      for (int j = 0; j < 4; ++j) {
        int g = g0 + tl * 16 + lh * 4 + j;
        float xv = acc[tl][j] + 512.0f;
        c[tl * 4 + j] = (g < gmax)
            ? ((__builtin_bit_cast(unsigned, xv) & 0xFFFFFC00u) |
               (unsigned)(1023 - g))
            : 0u;
      }
    SORT8(c, 0);
    SORT8(c, 8);
    unsigned e[8];
#pragma unroll
    for (int i = 0; i < 8; ++i) e[i] = umax_(c[i], c[15 - i]);
    CLEAN8(e);
    unsigned nv[8];
    nv[0] = umax_(v0, e[7]); nv[1] = umax_(v1, e[6]);
    nv[2] = umax_(v2, e[5]); nv[3] = umax_(v3, e[4]);
    nv[4] = umax_(v4, e[3]); nv[5] = umax_(v5, e[2]);
    nv[6] = umax_(v6, e[1]); nv[7] = umax_(v7, e[0]);
    CLEAN8(nv);
    v0 = nv[0]; v1 = nv[1]; v2 = nv[2]; v3 = nv[3];
    v4 = nv[4]; v5 = nv[5]; v6 = nv[6]; v7 = nv[7];
  }

#define MERGE4() \
  _Pragma("unroll") \
  for (int st = 0; st < 2; ++st) { \
    const int off = 16 << st; \
    unsigned p0 = (unsigned)__shfl_xor((int)v0, off, 64); \
    unsigned p1 = (unsigned)__shfl_xor((int)v1, off, 64); \
    unsigned p2 = (unsigned)__shfl_xor((int)v2, off, 64); \
    unsigned p3 = (unsigned)__shfl_xor((int)v3, off, 64); \
    unsigned p4 = (unsigned)__shfl_xor((int)v4, off, 64); \
    unsigned p5 = (unsigned)__shfl_xor((int)v5, off, 64); \
    unsigned p6 = (unsigned)__shfl_xor((int)v6, off, 64); \
    unsigned p7 = (unsigned)__shfl_xor((int)v7, off, 64); \
    unsigned w0 = umax_(v0, p7), w1 = umax_(v1, p6); \
    unsigned w2 = umax_(v2, p5), w3 = umax_(v3, p4); \
    unsigned w4 = umax_(v4, p3), w5 = umax_(v5, p2); \
    unsigned w6 = umax_(v6, p1), w7 = umax_(v7, p0); \
    CEx(w0, w4); CEx(w1, w5); CEx(w2, w6); CEx(w3, w7); \
    CEx(w0, w2); CEx(w1, w3); CEx(w4, w6); CEx(w5, w7); \
    CEx(w0, w1); CEx(w2, w3); CEx(w4, w5); CEx(w6, w7); \
    v0 = w0; v1 = w1; v2 = w2; v3 = w3; v4 = w4; v5 = w5; v6 = w6; v7 = w7; \
  }

  MERGE4();                                  // intra-wave: merge 4 lh-lanes

  if (lh == 0) {                             // wave-local result -> LDS
    unsigned* tp = &top[w][ll][0];
    tp[0] = v0; tp[1] = v1; tp[2] = v2; tp[3] = v3;
    tp[4] = v4; tp[5] = v5; tp[6] = v6; tp[7] = v7;
  }
  __syncthreads();                           // also drains zero-fill stores

  if (w < 2) {                               // phase 1: merge 4 lists each
    const unsigned* tp = &top[w * 4 + lh][ll][0];
    v0 = tp[0]; v1 = tp[1]; v2 = tp[2]; v3 = tp[3];
    v4 = tp[4]; v5 = tp[5]; v6 = tp[6]; v7 = tp[7];
    MERGE4();
    if (lh == 0) {
      unsigned* dp = &top[w * 4][ll][0];
      dp[0] = v0; dp[1] = v1; dp[2] = v2; dp[3] = v3;
      dp[4] = v4; dp[5] = v5; dp[6] = v6; dp[7] = v7;
    }
  }
  __syncthreads();

  if (w == 0) {                              // phase 2: merge the 2 + scatter
    const unsigned* tp = &top[(lh & 1) * 4][ll][0];
    v0 = tp[0]; v1 = tp[1]; v2 = tp[2]; v3 = tp[3];
    v4 = tp[4]; v5 = tp[5]; v6 = tp[6]; v7 = tp[7];
    {
      unsigned p0 = (unsigned)__shfl_xor((int)v0, 16, 64);
      unsigned p1 = (unsigned)__shfl_xor((int)v1, 16, 64);
      unsigned p2 = (unsigned)__shfl_xor((int)v2, 16, 64);
      unsigned p3 = (unsigned)__shfl_xor((int)v3, 16, 64);
      unsigned p4 = (unsigned)__shfl_xor((int)v4, 16, 64);
      unsigned p5 = (unsigned)__shfl_xor((int)v5, 16, 64);
      unsigned p6 = (unsigned)__shfl_xor((int)v6, 16, 64);
      unsigned p7 = (unsigned)__shfl_xor((int)v7, 16, 64);
      unsigned w0 = umax_(v0, p7), w1 = umax_(v1, p6);
      unsigned w2 = umax_(v2, p5), w3 = umax_(v3, p4);
      unsigned w4 = umax_(v4, p3), w5 = umax_(v5, p2);
      unsigned w6 = umax_(v6, p1), w7 = umax_(v7, p0);
      CEx(w0, w4); CEx(w1, w5); CEx(w2, w6); CEx(w3, w7);
      CEx(w0, w2); CEx(w1, w3); CEx(w4, w6); CEx(w5, w7);
      CEx(w0, w1); CEx(w2, w3); CEx(w4, w5); CEx(w6, w7);
      v0 = w0; v1 = w1; v2 = w2; v3 = w3; v4 = w4; v5 = w5; v6 = w6; v7 = w7;
    }
    if (lh == 0) {
      int* rb = mbase + (size_t)ll * G_;
      if (v0) rb[1023 - (v0 & 1023)] = 1;
      if (v1) rb[1023 - (v1 & 1023)] = 1;
      if (v2) rb[1023 - (v2 & 1023)] = 1;
      if (v3) rb[1023 - (v3 & 1023)] = 1;
      if (v4) rb[1023 - (v4 & 1023)] = 1;
      if (v5) rb[1023 - (v5 & 1023)] = 1;
      if (v6) rb[1023 - (v6 & 1023)] = 1;
      if (v7) rb[1023 - (v7 & 1023)] = 1;
    }
  }
#undef MERGE4
#undef CLEAN8
#undef SORT8
#undef CEx
}

extern "C" void kernel_launch(void* const* d_in, const int* in_sizes, int n_in,
                              void* d_out, int out_size, void* d_ws, size_t ws_size,
                              hipStream_t stream)
{
  const float* x   = (const float*)d_in[0];
  const float* wq  = (const float*)d_in[1];
  const float* wk  = (const float*)d_in[2];
  const float* wg  = (const float*)d_in[3];
  const float* ape = (const float*)d_in[4];

  // ws layout (bf16): Ws[1152][768] | q[16384][384] | keys[4096][384]
  bf16* Ws   = (bf16*)d_ws;
  bf16* qb   = Ws + (size_t)NS_ * E_;
  bf16* keys = qb + (size_t)MT_ * HD_;

  // x_bf16 staged in d_out (dead before the mask write overwrites it)
  bf16* xb = (bf16*)d_out;

  cvt_x_kernel<<<dim3(MT_ * E_ / 8 / 256), dim3(256), 0, stream>>>(x, xb);
  cvt_w_t<<<dim3(E_ / 32, HD_ / 32, 3), dim3(256), 0, stream>>>(wq, wk, wg, Ws);

  gemm_qkg_mfma<<<dim3(MT_ / 128, NS_ / 128), dim3(256), 0, stream>>>(
      xb, Ws, ape, qb, keys);

  score_topk_fused<<<dim3(256, B_), dim3(512), 0, stream>>>(
      qb, keys, (int*)d_out, (int*)d_out + (size_t)B_ * T_ * G_);
}

// Round 15
// 120.335 us; speedup vs baseline: 1.2331x; 1.1934x over previous
//
#include <hip/hip_runtime.h>
#include <hip/hip_bf16.h>
#include <math.h>

#define B_    4
#define T_    4096
#define E_    768
#define H_    6
#define D_    64
#define HD_   384
#define G_    1024
#define RATIO_ 4
#define TOPK_ 8
#define MT_   (B_*T_)   // 16384 rows total
#define NS_   1152      // stacked N: [384 q][768 kg-interleaved]

typedef __attribute__((ext_vector_type(8))) short short8;
typedef __attribute__((ext_vector_type(4))) float f32x4;
typedef __hip_bfloat16 bf16;

#define GLD16(g, l) __builtin_amdgcn_global_load_lds( \
    (const __attribute__((address_space(1))) void*)(g), \
    (__attribute__((address_space(3))) void*)(l), 16, 0, 0)

static __device__ __forceinline__ unsigned short f2bf(float f) {
  bf16 h = __float2bfloat16(f);
  return __builtin_bit_cast(unsigned short, h);
}
static __device__ __forceinline__ unsigned umax_(unsigned a, unsigned b) { return a > b ? a : b; }
static __device__ __forceinline__ unsigned umin_(unsigned a, unsigned b) { return a > b ? b : a; }

// ---------------------------------------------------------------------------
// x f32 -> bf16 (8 elems/thread)
// ---------------------------------------------------------------------------
__global__ __launch_bounds__(256) void cvt_x_kernel(
    const float* __restrict__ in, bf16* __restrict__ out)
{
  size_t i = (size_t)blockIdx.x * 256 + threadIdx.x;
  const float4* p = reinterpret_cast<const float4*>(in) + i * 2;
  float4 v0 = p[0], v1 = p[1];
  float f[8] = {v0.x, v0.y, v0.z, v0.w, v1.x, v1.y, v1.z, v1.w};
  union { unsigned short u[8]; short8 v; } r;
#pragma unroll
  for (int k = 0; k < 8; ++k) r.u[k] = f2bf(f[k]);
  *reinterpret_cast<short8*>(out + i * 8) = r.v;
}

// ---------------------------------------------------------------------------
// transpose+convert+STACK weights into Ws [1152][768] bf16:
//   q col c -> row c ; k col c -> row 384+(c>>4)*32+(c&15) ; g -> +16
// ---------------------------------------------------------------------------
__global__ __launch_bounds__(256) void cvt_w_t(
    const float* __restrict__ wq, const float* __restrict__ wk,
    const float* __restrict__ wg, bf16* __restrict__ outbase)
{
  const int z = blockIdx.z;
  const float* src = z == 0 ? wq : (z == 1 ? wk : wg);
  __shared__ float t[32][33];
  int r = threadIdx.x >> 5, c = threadIdx.x & 31;
  int k0 = blockIdx.x * 32, n0 = blockIdx.y * 32;
#pragma unroll
  for (int i = 0; i < 4; ++i)
    t[r + i * 8][c] = src[(size_t)(k0 + r + i * 8) * HD_ + n0 + c];
  __syncthreads();
#pragma unroll
  for (int i = 0; i < 4; ++i) {
    int cc = n0 + r + i * 8;
    int ro = (z == 0) ? cc : 384 + ((cc >> 4) << 5) + ((z - 1) << 4) + (cc & 15);
    outbase[(size_t)ro * E_ + k0 + c] = __float2bfloat16(t[c][r + i * 8]);
  }
}

// ---------------------------------------------------------------------------
// Fused projection GEMM, BK=64 (12 K-steps, HALF the barriers of BK=32):
// [MT x 768] @ Ws^T -> q (rmsnormed) + keys (pooled+rmsnormed).
// 128x128 tile, 4 waves stacked in M (wave 32x128, acc 2x8).
// A: direct global->reg prefetched 1 iter (4 short8/iter).
// B: 2-buf LDS ring (16KB/buf) + counted vmcnt:
//   queue [A(k)4, S(k)4, A(k+1)4, S(k+1)4] -> retire oldest 8 -> vmcnt(8).
// Staging swizzle on SOURCE slot (tid&7)^((tid>>3)&7); read slot
// (ks*4+lh)^(ll&7) -> 8 distinct 16B slots per 8 lanes = 2-way free.
// ---------------------------------------------------------------------------
__global__ __launch_bounds__(256, 3) void gemm_qkg_mfma(
    const bf16* __restrict__ X, const bf16* __restrict__ Ws,
    const float* __restrict__ ape, bf16* __restrict__ Q,
    bf16* __restrict__ keys)
{
  __shared__ bf16 lds[2][8192];   // [128 rows][64 k] per buf = 16KB
  const int tid = threadIdx.x;
  const int lane = tid & 63, wv = tid >> 6;
  const int ll = lane & 15, lh = lane >> 4;
  const int m0 = blockIdx.x * 128, n0 = blockIdx.y * 128;
  // staging: chunk c (4KB) = rows c*32..c*32+31; thread -> row tid>>3,
  // phys slot tid&7, source col-slot swizzled by row&7
  const int srow = tid >> 3;
  const int sslot = (((tid & 7) ^ ((tid >> 3) & 7)) << 3);
  const bf16* pS = Ws + (size_t)(n0 + srow) * E_ + sslot;
  const bf16* pA0 = X + (size_t)(m0 + wv * 32 + ll) * E_ + lh * 8;
  const bf16* pA1 = pA0 + (size_t)16 * E_;

#define STAGE(b, k0) do { \
    char* base_ = (char*)&lds[b][0] + tid * 16; \
    GLD16(pS + (k0),            base_); \
    GLD16(pS + 32 * E_ + (k0),  base_ + 4096); \
    GLD16(pS + 64 * E_ + (k0),  base_ + 8192); \
    GLD16(pS + 96 * E_ + (k0),  base_ + 12288); \
  } while (0)
#define LOAD_A(dst, k0) do { \
    dst[0][0] = *reinterpret_cast<const short8*>(pA0 + (k0)); \
    dst[0][1] = *reinterpret_cast<const short8*>(pA0 + (k0) + 32); \
    dst[1][0] = *reinterpret_cast<const short8*>(pA1 + (k0)); \
    dst[1][1] = *reinterpret_cast<const short8*>(pA1 + (k0) + 32); \
  } while (0)

  f32x4 acc[2][8];
#pragma unroll
  for (int m = 0; m < 2; ++m)
#pragma unroll
    for (int n = 0; n < 8; ++n) acc[m][n] = (f32x4){0.f, 0.f, 0.f, 0.f};

  short8 curA[2][2], nxtA[2][2];   // [m][ks]
  LOAD_A(curA, 0);                 // A(0): 4 loads
  STAGE(0, 0);                     // S(0): 4 loads
#pragma unroll
  for (int m = 0; m < 2; ++m)
#pragma unroll
    for (int s = 0; s < 2; ++s) nxtA[m][s] = curA[m][s];

#pragma unroll
  for (int k = 0; k < 12; ++k) {
    const int k0 = k * 64;
    if (k < 11) {
      LOAD_A(nxtA, k0 + 64);           // A(k+1)
      STAGE((k + 1) & 1, k0 + 64);     // S(k+1)
    }
    if (k < 11) asm volatile("s_waitcnt vmcnt(8)" ::: "memory");
    else        asm volatile("s_waitcnt vmcnt(0)" ::: "memory");
    __builtin_amdgcn_s_barrier();          // buf[k&1] fully staged
    __builtin_amdgcn_sched_barrier(0);
    const bf16* Lb = &lds[k & 1][0];
    // ks = 0 half
    short8 b0[8];
#pragma unroll
    for (int n = 0; n < 8; ++n)
      b0[n] = *reinterpret_cast<const short8*>(
          &Lb[(n * 16 + ll) * 64 + ((lh ^ (ll & 7)) << 3)]);
    asm volatile("s_waitcnt lgkmcnt(0)" ::: "memory");
    __builtin_amdgcn_sched_barrier(0);
#pragma unroll
    for (int m = 0; m < 2; ++m)
#pragma unroll
      for (int n = 0; n < 8; ++n)
        acc[m][n] = __builtin_amdgcn_mfma_f32_16x16x32_bf16(curA[m][0], b0[n], acc[m][n], 0, 0, 0);
    // ks = 1 half
    short8 b1[8];
#pragma unroll
    for (int n = 0; n < 8; ++n)
      b1[n] = *reinterpret_cast<const short8*>(
          &Lb[(n * 16 + ll) * 64 + (((4 + lh) ^ (ll & 7)) << 3)]);
    asm volatile("s_waitcnt lgkmcnt(0)" ::: "memory");
    __builtin_amdgcn_sched_barrier(0);
    __builtin_amdgcn_s_barrier();          // all reads of buf[k&1] done
#pragma unroll
    for (int m = 0; m < 2; ++m)
#pragma unroll
      for (int n = 0; n < 8; ++n)
        acc[m][n] = __builtin_amdgcn_mfma_f32_16x16x32_bf16(curA[m][1], b1[n], acc[m][n], 0, 0, 0);
#pragma unroll
    for (int m = 0; m < 2; ++m)
#pragma unroll
      for (int s = 0; s < 2; ++s) curA[m][s] = nxtA[m][s];
  }
#undef STAGE
#undef LOAD_A

  if (blockIdx.y < 3) {
    // q epilogue: 2 heads per wave; rmsnorm each 64-col head
#pragma unroll
    for (int m = 0; m < 2; ++m)
#pragma unroll
      for (int j = 0; j < 4; ++j) {
        int row = m0 + wv * 32 + m * 16 + lh * 4 + j;
#pragma unroll
        for (int h = 0; h < 2; ++h) {
          float ss = 0.f;
#pragma unroll
          for (int n = 4 * h; n < 4 * h + 4; ++n) ss += acc[m][n][j] * acc[m][n][j];
          ss += __shfl_xor(ss, 1, 64); ss += __shfl_xor(ss, 2, 64);
          ss += __shfl_xor(ss, 4, 64); ss += __shfl_xor(ss, 8, 64);
          float scl = rsqrtf(ss * (1.0f / D_) + 1e-6f);
#pragma unroll
          for (int n = 4 * h; n < 4 * h + 4; ++n)
            Q[(size_t)row * HD_ + n0 + n * 16 + ll] =
                __float2bfloat16(acc[m][n][j] * scl);
        }
      }
  } else {
    // kg epilogue: frags alternate k,g; pool 4 pairs = full head
    const int hcb = (n0 - 384) >> 1;
    float apev[4][4];
#pragma unroll
    for (int p = 0; p < 4; ++p) {
      int hc = hcb + p * 16 + ll;
#pragma unroll
      for (int j = 0; j < 4; ++j) apev[p][j] = ape[j * HD_ + hc];
    }
#pragma unroll
    for (int m = 0; m < 2; ++m) {
      float pooled[4];
#pragma unroll
      for (int p = 0; p < 4; ++p) {
        float g0 = acc[m][2 * p + 1][0] + apev[p][0];
        float g1 = acc[m][2 * p + 1][1] + apev[p][1];
        float g2 = acc[m][2 * p + 1][2] + apev[p][2];
        float g3 = acc[m][2 * p + 1][3] + apev[p][3];
        float mx = fmaxf(fmaxf(g0, g1), fmaxf(g2, g3));
        float e0 = expf(g0 - mx), e1 = expf(g1 - mx);
        float e2 = expf(g2 - mx), e3 = expf(g3 - mx);
        float inv = 1.0f / (e0 + e1 + e2 + e3);
        pooled[p] = (acc[m][2 * p][0] * e0 + acc[m][2 * p][1] * e1 +
                     acc[m][2 * p][2] * e2 + acc[m][2 * p][3] * e3) * inv;
      }
      float ss = pooled[0] * pooled[0] + pooled[1] * pooled[1] +
                 pooled[2] * pooled[2] + pooled[3] * pooled[3];
      ss += __shfl_xor(ss, 1, 64); ss += __shfl_xor(ss, 2, 64);
      ss += __shfl_xor(ss, 4, 64); ss += __shfl_xor(ss, 8, 64);
      float scl = rsqrtf(ss * (1.0f / D_) + 1e-6f);
      int prow = (m0 >> 2) + wv * 8 + m * 4 + lh;
#pragma unroll
      for (int p = 0; p < 4; ++p)
        keys[(size_t)prow * HD_ + hcb + p * 16 + ll] =
            __float2bfloat16(pooled[p] * scl);
    }
  }
}

// ---------------------------------------------------------------------------
// FUSED score + top-8 + mask write — EXACT R11 config (proven 63.6us):
// 4 waves/block, 256 threads, grid (256, B_). Swapped MFMA, per-lane serial
// top-8 insert, intra-wave bitonic merge, single-phase LDS merge by wave 0.
// ---------------------------------------------------------------------------
__global__ __launch_bounds__(256, 4) void score_topk_fused(
    const bf16* __restrict__ Qall, const bf16* __restrict__ Kall,
    int* __restrict__ mask, int* __restrict__ ends)
{
  const int x = blockIdx.x;                 // 0..255
  const int b = blockIdx.y;                 // batch
  const int s = (b < 2) ? x : 255 - x;      // complementary balance pairing
  const int t0 = s << 4;
  const int tid = threadIdx.x;
  const int w = tid >> 6;                   // wave 0..3
  const int lane = tid & 63;
  const int ll = lane & 15, lh = lane >> 4;

  __shared__ unsigned top[4][16][8];        // per-wave top-8 per row

  if (x == 0 && b == 0) {                   // group_ends (once)
    int g = tid;
#pragma unroll
    for (int c = 0; c < 4; ++c, g += 256) {
      int e = (g << 2) + 3;
      ends[g] = e < T_ - 1 ? e : T_ - 1;
    }
  }

  // zero-fill the strip's 16 mask rows (overlaps compute; drained by sync)
  int* mbase = mask + ((size_t)b * T_ + t0) * G_;
  {
    int4* m4 = reinterpret_cast<int4*>(mbase);
    const int4 z = make_int4(0, 0, 0, 0);
#pragma unroll
    for (int i = 0; i < 16; ++i) m4[i * 256 + tid] = z;
  }

  const bf16* Qb = Qall + (size_t)b * T_ * HD_;
  const bf16* Kb = Kall + (size_t)b * G_ * HD_;
  const int t = t0 + ll;                    // this lane's row
  const int gmax = (t + 1) >> 2;
  const int nmega = ((t0 >> 2) + 4 + 63) >> 6;   // 64-g mega-tiles in strip

  // q panel: 12 k-frags (B-operand: col=ll -> t, k-slice lh*8)
  short8 qf[12];
  {
    const bf16* pQ = Qb + (size_t)t * HD_ + lh * 8;
#pragma unroll
    for (int k = 0; k < 12; ++k)
      qf[k] = *reinterpret_cast<const short8*>(pQ + k * 32);
  }

  unsigned v0 = 0, v1 = 0, v2 = 0, v3 = 0, v4 = 0, v5 = 0, v6 = 0, v7 = 0;
#define INS(xx) do { unsigned k_ = (xx), t_; \
    t_ = umax_(v0, k_); k_ = umin_(v0, k_); v0 = t_; \
    t_ = umax_(v1, k_); k_ = umin_(v1, k_); v1 = t_; \
    t_ = umax_(v2, k_); k_ = umin_(v2, k_); v2 = t_; \
    t_ = umax_(v3, k_); k_ = umin_(v3, k_); v3 = t_; \
    t_ = umax_(v4, k_); k_ = umin_(v4, k_); v4 = t_; \
    t_ = umax_(v5, k_); k_ = umin_(v5, k_); v5 = t_; \
    t_ = umax_(v6, k_); k_ = umin_(v6, k_); v6 = t_; \
    t_ = umax_(v7, k_); k_ = umin_(v7, k_); v7 = t_; } while (0)

  for (int mg = w; mg < nmega; mg += 4) {   // waves split mega-tiles
    const int g0 = mg << 6;
    const bf16* pK = Kb + (size_t)(g0 + ll) * HD_ + lh * 8;
    short8 kf[12][4];
#pragma unroll
    for (int kk = 0; kk < 12; ++kk)
#pragma unroll
      for (int tl = 0; tl < 4; ++tl)
        kf[kk][tl] = *reinterpret_cast<const short8*>(
            pK + (size_t)tl * 16 * HD_ + kk * 32);
    f32x4 acc[4];
#pragma unroll
    for (int tl = 0; tl < 4; ++tl) acc[tl] = (f32x4){0.f, 0.f, 0.f, 0.f};
#pragma unroll
    for (int kk = 0; kk < 12; ++kk)
#pragma unroll
      for (int tl = 0; tl < 4; ++tl)
        acc[tl] = __builtin_amdgcn_mfma_f32_16x16x32_bf16(
            kf[kk][tl], qf[kk], acc[tl], 0, 0, 0);
    // |dot| < 384 (Cauchy-Schwarz, rmsnorm'd operands) -> dot+512 > 0:
    // positive f32 bits are order-isomorphic to u32.
#pragma unroll
    for (int tl = 0; tl < 4; ++tl)
#pragma unroll
      for (int j = 0; j < 4; ++j) {
        int g = g0 + tl * 16 + lh * 4 + j;
        float xv = acc[tl][j] + 512.0f;
        unsigned key = (g < gmax)
            ? ((__builtin_bit_cast(unsigned, xv) & 0xFFFFFC00u) |
               (unsigned)(1023 - g))
            : 0u;
        INS(key);
      }
  }
#undef INS

#define CEx(a, bb) { unsigned h_ = umax_(a, bb), l_ = umin_(a, bb); a = h_; bb = l_; }
#define MERGE4() \
  _Pragma("unroll") \
  for (int st = 0; st < 2; ++st) { \
    const int off = 16 << st; \
    unsigned p0 = (unsigned)__shfl_xor((int)v0, off, 64); \
    unsigned p1 = (unsigned)__shfl_xor((int)v1, off, 64); \
    unsigned p2 = (unsigned)__shfl_xor((int)v2, off, 64); \
    unsigned p3 = (unsigned)__shfl_xor((int)v3, off, 64); \
    unsigned p4 = (unsigned)__shfl_xor((int)v4, off, 64); \
    unsigned p5 = (unsigned)__shfl_xor((int)v5, off, 64); \
    unsigned p6 = (unsigned)__shfl_xor((int)v6, off, 64); \
    unsigned p7 = (unsigned)__shfl_xor((int)v7, off, 64); \
    unsigned w0 = umax_(v0, p7), w1 = umax_(v1, p6); \
    unsigned w2 = umax_(v2, p5), w3 = umax_(v3, p4); \
    unsigned w4 = umax_(v4, p3), w5 = umax_(v5, p2); \
    unsigned w6 = umax_(v6, p1), w7 = umax_(v7, p0); \
    CEx(w0, w4); CEx(w1, w5); CEx(w2, w6); CEx(w3, w7); \
    CEx(w0, w2); CEx(w1, w3); CEx(w4, w6); CEx(w5, w7); \
    CEx(w0, w1); CEx(w2, w3); CEx(w4, w5); CEx(w6, w7); \
    v0 = w0; v1 = w1; v2 = w2; v3 = w3; v4 = w4; v5 = w5; v6 = w6; v7 = w7; \
  }

  MERGE4();                                  // intra-wave: merge 4 lh-lanes

  if (lh == 0) {                             // wave-local result -> LDS
    unsigned* tp = &top[w][ll][0];
    tp[0] = v0; tp[1] = v1; tp[2] = v2; tp[3] = v3;
    tp[4] = v4; tp[5] = v5; tp[6] = v6; tp[7] = v7;
  }
  __syncthreads();                           // also drains zero-fill stores

  if (w == 0) {                              // inter-wave merge + scatter
    const unsigned* tp = &top[lh][ll][0];
    v0 = tp[0]; v1 = tp[1]; v2 = tp[2]; v3 = tp[3];
    v4 = tp[4]; v5 = tp[5]; v6 = tp[6]; v7 = tp[7];
    MERGE4();
    if (lh == 0) {
      int* rb = mbase + (size_t)ll * G_;
      if (v0) rb[1023 - (v0 & 1023)] = 1;
      if (v1) rb[1023 - (v1 & 1023)] = 1;
      if (v2) rb[1023 - (v2 & 1023)] = 1;
      if (v3) rb[1023 - (v3 & 1023)] = 1;
      if (v4) rb[1023 - (v4 & 1023)] = 1;
      if (v5) rb[1023 - (v5 & 1023)] = 1;
      if (v6) rb[1023 - (v6 & 1023)] = 1;
      if (v7) rb[1023 - (v7 & 1023)] = 1;
    }
  }
#undef MERGE4
#undef CEx
}

extern "C" void kernel_launch(void* const* d_in, const int* in_sizes, int n_in,
                              void* d_out, int out_size, void* d_ws, size_t ws_size,
                              hipStream_t stream)
{
  const float* x   = (const float*)d_in[0];
  const float* wq  = (const float*)d_in[1];
  const float* wk  = (const float*)d_in[2];
  const float* wg  = (const float*)d_in[3];
  const float* ape = (const float*)d_in[4];

  // ws layout (bf16): Ws[1152][768] | q[16384][384] | keys[4096][384]
  bf16* Ws   = (bf16*)d_ws;
  bf16* qb   = Ws + (size_t)NS_ * E_;
  bf16* keys = qb + (size_t)MT_ * HD_;

  // x_bf16 staged in d_out (dead before the mask write overwrites it)
  bf16* xb = (bf16*)d_out;

  cvt_x_kernel<<<dim3(MT_ * E_ / 8 / 256), dim3(256), 0, stream>>>(x, xb);
  cvt_w_t<<<dim3(E_ / 32, HD_ / 32, 3), dim3(256), 0, stream>>>(wq, wk, wg, Ws);

  gemm_qkg_mfma<<<dim3(MT_ / 128, NS_ / 128), dim3(256), 0, stream>>>(
      xb, Ws, ape, qb, keys);

  score_topk_fused<<<dim3(256, B_), dim3(256), 0, stream>>>(
      qb, keys, (int*)d_out, (int*)d_out + (size_t)B_ * T_ * G_);
}